// Round 7
// baseline (2748.589 us; speedup 1.0000x reference)
//
#include <hip/hip_runtime.h>
#include <stdint.h>
#include <float.h>

#define NUM_SAMPLES 50
#define EPSF 1e-8f
#define PENALTY 1e-4f
#define REV_SCALE 0.1f

// grid 1: original vertices (N(0,1) coords)
#define G1 48
#define G1LO -5.0f
#define G1HI 5.0f
#define NCELL1 (G1*G1*G1)
// grid 2: original-face barycenters (sigma ~0.577)
#define G2 48
#define G2LO -3.5f
#define G2HI 3.5f
#define NCELL2 (G2*G2*G2)

#define NTOT2 (NCELL1 + NCELL2)       // 221184
#define SCAN_BLOCKS (NTOT2 / 1024)    // 216 (co-resident on 256 CUs)
static_assert(NTOT2 % 1024 == 0, "scan tiling");

#define GS 16          // lanes per forward query group

// acc region (floats): fwd slots [0..1023] stride16; rev [1024..2047]; max bits [2048..3071];
// done counter int at [3072]. 16 KB.
#define ACC_FLOATS 4096

// ---------------- JAX threefry2x32 (exact) ----------------
__device__ __forceinline__ uint32_t rotl32(uint32_t v, int d) {
  return (v << d) | (v >> (32 - d));
}

__device__ __forceinline__ void threefry2x32(uint32_t k0, uint32_t k1,
                                             uint32_t x0, uint32_t x1,
                                             uint32_t& o0, uint32_t& o1) {
  const uint32_t k2 = k0 ^ k1 ^ 0x1BD11BDAu;
  x0 += k0; x1 += k1;
#define TF_ROUND(r) { x0 += x1; x1 = rotl32(x1, (r)); x1 ^= x0; }
  TF_ROUND(13) TF_ROUND(15) TF_ROUND(26) TF_ROUND(6)
  x0 += k1; x1 += k2 + 1u;
  TF_ROUND(17) TF_ROUND(29) TF_ROUND(16) TF_ROUND(24)
  x0 += k2; x1 += k0 + 2u;
  TF_ROUND(13) TF_ROUND(15) TF_ROUND(26) TF_ROUND(6)
  x0 += k0; x1 += k1 + 3u;
  TF_ROUND(17) TF_ROUND(29) TF_ROUND(16) TF_ROUND(24)
  x0 += k1; x1 += k2 + 4u;
  TF_ROUND(13) TF_ROUND(15) TF_ROUND(26) TF_ROUND(6)
  x0 += k2; x1 += k0 + 5u;
#undef TF_ROUND
  o0 = x0; o1 = x1;
}

__device__ __forceinline__ float bits_to_uniform(uint32_t bits) {
  return __uint_as_float((bits >> 9) | 0x3f800000u) - 1.0f;
}

__device__ __forceinline__ float jax_uniform_at(uint32_t k0, uint32_t k1, uint32_t idx) {
  uint32_t o0, o1;
  threefry2x32(k0, k1, 0u, idx, o0, o1);
  return bits_to_uniform(o0 ^ o1);
}

__device__ __forceinline__ int cell_coord(float p, float lo, float invh, int G) {
  int i = (int)floorf((p - lo) * invh);
  return min(max(i, 0), G - 1);
}

// ---------------- prep: histograms only (vertices -> G1, orig barycenters -> G2)
__global__ __launch_bounds__(256) void prep_kernel(
    const float* __restrict__ ov, const int* __restrict__ ofc,
    int* __restrict__ cnt, int NOF, int NOV) {
  int i = blockIdx.x * blockDim.x + threadIdx.x;
  if (i >= NOF + NOV) return;
  if (i < NOF) {
    int a = ofc[3*i], b = ofc[3*i+1], c = ofc[3*i+2];
    float x = (ov[3*a]   + ov[3*b]   + ov[3*c])   / 3.0f;
    float y = (ov[3*a+1] + ov[3*b+1] + ov[3*c+1]) / 3.0f;
    float z = (ov[3*a+2] + ov[3*b+2] + ov[3*c+2]) / 3.0f;
    const float invh = (float)G2 / (G2HI - G2LO);
    int cx = cell_coord(x, G2LO, invh, G2);
    int cy = cell_coord(y, G2LO, invh, G2);
    int cz = cell_coord(z, G2LO, invh, G2);
    atomicAdd(&cnt[NCELL1 + (cz*G2 + cy)*G2 + cx], 1);
  } else {
    int j = i - NOF;
    float x = ov[3*j], y = ov[3*j+1], z = ov[3*j+2];
    const float invh = (float)G1 / (G1HI - G1LO);
    int cx = cell_coord(x, G1LO, invh, G1);
    int cy = cell_coord(y, G1LO, invh, G1);
    int cz = cell_coord(z, G1LO, invh, G1);
    atomicAdd(&cnt[(cz*G1 + cy)*G1 + cx], 1);
  }
}

// ---------------- fused parallel scan (publish aggregate + parallel poll); 216 blocks
__global__ __launch_bounds__(256) void scan_kernel(
    const int4* __restrict__ cnt4, unsigned long long* __restrict__ gsum,
    int* __restrict__ cs, int* __restrict__ cur) {
  __shared__ int lds[256];
  __shared__ int wsum[4];
  __shared__ int boffS;
  int t = threadIdx.x;
  int gid = blockIdx.x * 256 + t;
  int4 c = cnt4[gid];
  int s01 = c.x + c.y;
  int tsum = s01 + c.z + c.w;
  lds[t] = tsum;
  __syncthreads();
  for (int d = 1; d < 256; d <<= 1) {
    int u = (t >= d) ? lds[t - d] : 0;
    __syncthreads();
    lds[t] += u;
    __syncthreads();
  }
  int incl = lds[t];
  int agg  = lds[255];
  if (t == 0)
    atomicExch(&gsum[blockIdx.x], (1ULL << 63) | (unsigned long long)(unsigned)agg);
  int pre = 0;
  if (t < (int)blockIdx.x) {
    unsigned long long v;
    do { v = atomicAdd(&gsum[t], 0ULL); } while (!(v >> 63));
    pre = (int)(v & 0xFFFFFFFFULL);
  }
  for (int o = 32; o > 0; o >>= 1) pre += __shfl_down(pre, o);
  if ((t & 63) == 0) wsum[t >> 6] = pre;
  __syncthreads();
  if (t == 0) boffS = wsum[0] + wsum[1] + wsum[2] + wsum[3];
  __syncthreads();
  int base = boffS + incl - tsum;
  int4 o4;
  o4.x = base;
  o4.y = base + c.x;
  o4.z = base + s01;
  o4.w = base + s01 + c.z;
  ((int4*)cs)[gid] = o4;
  ((int4*)cur)[gid] = o4;
  if (blockIdx.x == gridDim.x - 1 && t == 255) cs[NTOT2] = boffS + incl;
}

// ---------------- scatter 50K points (vertices + orig barycenters) into cell order
__global__ __launch_bounds__(256) void scatter_kernel(
    const float* __restrict__ ov, const int* __restrict__ ofc,
    int* __restrict__ cur, float4* __restrict__ sorted, int NOV, int NOF) {
  int i = blockIdx.x * blockDim.x + threadIdx.x;
  if (i >= NOV + NOF) return;
  float x, y, z; int cell;
  if (i < NOV) {
    x = ov[3*i]; y = ov[3*i+1]; z = ov[3*i+2];
    const float invh = (float)G1 / (G1HI - G1LO);
    int cx = cell_coord(x, G1LO, invh, G1);
    int cy = cell_coord(y, G1LO, invh, G1);
    int cz = cell_coord(z, G1LO, invh, G1);
    cell = (cz*G1 + cy)*G1 + cx;
  } else {
    int j = i - NOV;
    int a = ofc[3*j], b = ofc[3*j+1], c = ofc[3*j+2];
    x = (ov[3*a]   + ov[3*b]   + ov[3*c])   / 3.0f;
    y = (ov[3*a+1] + ov[3*b+1] + ov[3*c+1]) / 3.0f;
    z = (ov[3*a+2] + ov[3*b+2] + ov[3*c+2]) / 3.0f;
    const float invh = (float)G2 / (G2HI - G2LO);
    int cx = cell_coord(x, G2LO, invh, G2);
    int cy = cell_coord(y, G2LO, invh, G2);
    int cz = cell_coord(z, G2LO, invh, G2);
    cell = NCELL1 + (cz*G2 + cy)*G2 + cx;
  }
  int idx = atomicAdd(&cur[cell], 1);
  sorted[idx] = make_float4(x, y, z, x*x + y*y + z*z);
}

// ---------------- forward: row-parallel 16-lane 1-NN (unchanged from R6)
__device__ __forceinline__ float group_min16(float v) {
  for (int o = 8; o > 0; o >>= 1) v = fminf(v, __shfl_xor(v, o, 16));
  return v;
}

__device__ float nn_group(float px, float py, float pz, float q2,
                          const int* __restrict__ cs, const float4* __restrict__ pts,
                          int G, float lo, float h, int cellofs, int lane) {
  const float invh = 1.0f / h;
  int ix = cell_coord(px, lo, invh, G);
  int iy = cell_coord(py, lo, invh, G);
  int iz = cell_coord(pz, lo, invh, G);
  float m2x = -2.0f*px, m2y = -2.0f*py, m2z = -2.0f*pz;
  float best = FLT_MAX;
  {
    int cix = cellofs + (iz*G + iy)*G + ix;
    int s = cs[cix], e = cs[cix + 1];
    for (int i = s + lane; i < e; i += GS) {
      float4 v = pts[i];
      best = fminf(best, fmaf(v.z, m2z, fmaf(v.y, m2y, fmaf(v.x, m2x, v.w))));
    }
  }
  for (int r = 1; r < G; ++r) {
    float bmin = group_min16(best);
    float bd = (float)(r - 1) * h;
    if (bmin + q2 <= bd * bd) break;
    float dbest = bmin + q2;
    int z0 = max(iz - r, 0), z1 = min(iz + r, G - 1);
    int y0 = max(iy - r, 0), y1 = min(iy + r, G - 1);
    int x0 = max(ix - r, 0), x1 = min(ix + r, G - 1);
    int Y = y1 - y0 + 1;
    int nrows = Y * (z1 - z0 + 1);
    for (int rowi = lane; rowi < nrows; rowi += GS) {
      int zz = z0 + rowi / Y;
      int yy = y0 + rowi % Y;
      int adz = abs(zz - iz), ady = abs(yy - iy);
      float lbz = (adz > 0) ? (float)(adz - 1) * h : 0.0f;
      float lby = (ady > 0) ? (float)(ady - 1) * h : 0.0f;
      float lb2 = lbz*lbz + lby*lby;
      int rowbase = cellofs + (zz*G + yy)*G;
      if (adz == r || ady == r) {
        if (lb2 >= dbest) continue;
        int s = cs[rowbase + x0], e = cs[rowbase + x1 + 1];
        for (int i = s; i < e; ++i) {
          float4 v = pts[i];
          best = fminf(best, fmaf(v.z, m2z, fmaf(v.y, m2y, fmaf(v.x, m2x, v.w))));
        }
      } else {
        float lbx = (float)(r - 1) * h;
        if (lb2 + lbx*lbx >= dbest) continue;
        if (ix - r >= 0) {
          int cix = rowbase + ix - r;
          int s = cs[cix], e = cs[cix + 1];
          for (int i = s; i < e; ++i) {
            float4 v = pts[i];
            best = fminf(best, fmaf(v.z, m2z, fmaf(v.y, m2y, fmaf(v.x, m2x, v.w))));
          }
        }
        if (ix + r <= G - 1) {
          int cix = rowbase + ix + r;
          int s = cs[cix], e = cs[cix + 1];
          for (int i = s; i < e; ++i) {
            float4 v = pts[i];
            best = fminf(best, fmaf(v.z, m2z, fmaf(v.y, m2y, fmaf(v.x, m2x, v.w))));
          }
        }
      }
    }
  }
  return group_min16(best);
}

// ---------------- fused queries: fwd groups (16 lanes) + rev (one wave per face)
__global__ __launch_bounds__(256) void query_kernel(
    const float* __restrict__ ov, const float* __restrict__ sv,
    const int* __restrict__ sfc, const float* __restrict__ fp,
    const int* __restrict__ cs, const float4* __restrict__ sorted,
    float* __restrict__ acc, float* __restrict__ out,
    int NSF, int NFP, int fwdBlocks) {
  const float h1 = (G1HI - G1LO) / (float)G1;
  const float h2 = (G2HI - G2LO) / (float)G2;
  float facc = 0.0f, racc = 0.0f, rmaxv = 0.0f;

  if ((int)blockIdx.x < fwdBlocks) {
    // ---- forward: simplified-face barycenter -> nearest original barycenter ----
    int lane = threadIdx.x & (GS - 1);
    int g = blockIdx.x * (256 / GS) + threadIdx.x / GS;
    if (g < NSF) {
      int a = sfc[3*g], b = sfc[3*g+1], c = sfc[3*g+2];
      float x = (sv[3*a]   + sv[3*b]   + sv[3*c])   / 3.0f;
      float y = (sv[3*a+1] + sv[3*b+1] + sv[3*c+1]) / 3.0f;
      float z = (sv[3*a+2] + sv[3*b+2] + sv[3*c+2]) / 3.0f;
      float q2 = x*x + y*y + z*z;
      float best = nn_group(x, y, z, q2, cs, sorted, G2, G2LO, h2, NCELL1, lane);
      if (lane == 0) {
        float mind = sqrtf(fmaxf(best + q2, 0.0f));
        float p = (g < NFP) ? fp[g] : 0.0f;
        facc = p * mind;
      }
    }
  } else {
    // ---- reverse: one wave per simplified face; 64 lanes cooperate ----
    int lane = threadIdx.x & 63;
    int face = ((int)blockIdx.x - fwdBlocks) * 4 + (threadIdx.x >> 6);
    if (face < NSF) {
      // sample for this lane (lanes >= NUM_SAMPLES duplicate sample 0 with weight 0)
      int sid = face * NUM_SAMPLES + (lane < NUM_SAMPLES ? lane : 0);
      uint32_t a0, a1, b0, b1;
      threefry2x32(0u, 42u, 0u, 0u, a0, a1);  // rk1 = split(key(42))[0]
      threefry2x32(0u, 42u, 0u, 1u, b0, b1);  // rk2 = split(key(42))[1]
      float r1 = jax_uniform_at(a0, a1, (uint32_t)sid);
      float r2 = jax_uniform_at(b0, b1, (uint32_t)sid);
      float sr1 = sqrtf(r1);
      float ca = 1.0f - sr1;
      float cb = sr1 * (1.0f - r2);
      float cc = sr1 * r2;
      int va = sfc[3*face], vb = sfc[3*face+1], vc = sfc[3*face+2];
      float ax = sv[3*va], ay = sv[3*va+1], az = sv[3*va+2];
      float bx = sv[3*vb], by = sv[3*vb+1], bz = sv[3*vb+2];
      float cx = sv[3*vc], cy = sv[3*vc+1], cz = sv[3*vc+2];
      float px = ca*ax + cb*bx + cc*cx;
      float py = ca*ay + cb*by + cc*cy;
      float pz = ca*az + cb*bz + cc*cz;
      float w = (face < NFP && lane < NUM_SAMPLES) ? fp[face] : 0.0f;
      float q2 = px*px + py*py + pz*pz;
      float m2x = -2.0f*px, m2y = -2.0f*py, m2z = -2.0f*pz;

      // triangle AABB in G1 cells (samples are convex combos -> inside box)
      const float invh = 1.0f / h1;
      int bx0 = cell_coord(fminf(ax, fminf(bx, cx)), G1LO, invh, G1);
      int bx1 = cell_coord(fmaxf(ax, fmaxf(bx, cx)), G1LO, invh, G1);
      int by0 = cell_coord(fminf(ay, fminf(by, cy)), G1LO, invh, G1);
      int by1 = cell_coord(fmaxf(ay, fmaxf(by, cy)), G1LO, invh, G1);
      int bz0 = cell_coord(fminf(az, fminf(bz, cz)), G1LO, invh, G1);
      int bz1 = cell_coord(fmaxf(az, fmaxf(bz, cz)), G1LO, invh, G1);

      float best = FLT_MAX;
      int px0 = 0, px1 = -1, py0 = 0, py1 = -1, pz0 = 0, pz1 = -1;  // empty prev
      for (int r = 0; r < G1; ++r) {
        int ax0 = max(bx0 - r, 0), ax1 = min(bx1 + r, G1 - 1);
        int ay0 = max(by0 - r, 0), ay1 = min(by1 + r, G1 - 1);
        int az0 = max(bz0 - r, 0), az1 = min(bz1 + r, G1 - 1);
        float waveMax = FLT_MAX;
        if (r > 0) {
          float m = best + q2;
          for (int o = 32; o > 0; o >>= 1) m = fmaxf(m, __shfl_xor(m, o));
          float bd = (float)(r - 1) * h1;
          if (m <= bd * bd) break;                 // exact termination
          if (ax0 == px0 && ax1 == px1 && ay0 == py0 && ay1 == py1 &&
              az0 == pz0 && az1 == pz1) break;     // grid fully covered
          waveMax = m;
        }
        int EX = ax1 - ax0 + 1, EY = ay1 - ay0 + 1;
        int vol = EX * EY * (az1 - az0 + 1);
        for (int base = 0; base < vol; base += 64) {
          int li = base + lane;
          int s = 0, e = 0;
          if (li < vol) {
            int xx = li % EX; int tmp = li / EX;
            int yy = tmp % EY; int zz = tmp / EY;
            int gx = ax0 + xx, gy = ay0 + yy, gz = az0 + zz;
            bool inPrev = gx >= px0 && gx <= px1 && gy >= py0 && gy <= py1 &&
                          gz >= pz0 && gz <= pz1;
            if (!inPrev) {
              int cdx = max(max(bx0 - gx, gx - bx1), 0);
              int cdy = max(max(by0 - gy, gy - by1), 0);
              int cdz = max(max(bz0 - gz, gz - bz1), 0);
              float gxp = (cdx > 0) ? (float)(cdx - 1) * h1 : 0.0f;
              float gyp = (cdy > 0) ? (float)(cdy - 1) * h1 : 0.0f;
              float gzp = (cdz > 0) ? (float)(cdz - 1) * h1 : 0.0f;
              float lb2 = gxp*gxp + gyp*gyp + gzp*gzp;
              if (lb2 < waveMax) {
                int cell = (gz*G1 + gy)*G1 + gx;
                s = cs[cell]; e = cs[cell + 1];
              }
            }
          }
          unsigned long long mask = __ballot(s < e);
          while (mask) {
            int ci = __ffsll((unsigned long long)mask) - 1;
            mask &= mask - 1;
            int sC = __shfl(s, ci), eC = __shfl(e, ci);
            for (int j = sC; j < eC; ++j) {
              float4 v = sorted[j];   // wave-uniform broadcast load
              best = fminf(best, fmaf(v.z, m2z, fmaf(v.y, m2y, fmaf(v.x, m2x, v.w))));
            }
          }
        }
        px0 = ax0; px1 = ax1; py0 = ay0; py1 = ay1; pz0 = az0; pz1 = az1;
      }
      float d = sqrtf(fmaxf(best + q2, 0.0f));
      racc = w * d;
      rmaxv = d;
    }
  }

  // ---- block reduce + slot atomics + last-block finalize ----
  __shared__ float sF[4], sR[4], sM[4];
  __shared__ int isLast;
  __shared__ float stash[4];
  for (int o = 32; o > 0; o >>= 1) {
    facc += __shfl_down(facc, o);
    racc += __shfl_down(racc, o);
    rmaxv = fmaxf(rmaxv, __shfl_down(rmaxv, o));
  }
  int wid = threadIdx.x >> 6;
  if ((threadIdx.x & 63) == 0) { sF[wid] = facc; sR[wid] = racc; sM[wid] = rmaxv; }
  __syncthreads();
  if (threadIdx.x == 0) {
    float tf = sF[0] + sF[1] + sF[2] + sF[3];
    float tr = sR[0] + sR[1] + sR[2] + sR[3];
    float tm = fmaxf(fmaxf(sM[0], sM[1]), fmaxf(sM[2], sM[3]));
    int slot = (blockIdx.x & 63) * 16;
    atomicAdd(&acc[slot], tf);
    atomicAdd(&acc[1024 + slot], tr);
    atomicMax((int*)acc + 2048 + slot, __float_as_int(tm));
    __threadfence();
    int old = atomicAdd((int*)acc + 3072, 1);
    isLast = (old == (int)gridDim.x - 1) ? 1 : 0;
  }
  __syncthreads();
  if (!isLast) return;

  __shared__ float red[256];
  int t = threadIdx.x;
  float fsum = 0.0f, rsum = 0.0f, rmx = 0.0f;
  if (t < 64)        fsum = atomicAdd(&acc[t * 16], 0.0f);
  else if (t < 128)  rsum = atomicAdd(&acc[1024 + (t - 64) * 16], 0.0f);
  else if (t < 192)  rmx  = __int_as_float(atomicMax((int*)acc + 2048 + (t - 128) * 16, 0));
  float sfp = 0.0f;
  for (int i = t; i < NSF; i += 256) sfp += (i < NFP) ? fp[i] : 0.0f;

  red[t] = fsum; __syncthreads();
  for (int o = 128; o > 0; o >>= 1) { if (t < o) red[t] += red[t + o]; __syncthreads(); }
  if (t == 0) stash[0] = red[0];
  __syncthreads();
  red[t] = rsum; __syncthreads();
  for (int o = 128; o > 0; o >>= 1) { if (t < o) red[t] += red[t + o]; __syncthreads(); }
  if (t == 0) stash[1] = red[0];
  __syncthreads();
  red[t] = rmx; __syncthreads();
  for (int o = 128; o > 0; o >>= 1) { if (t < o) red[t] = fmaxf(red[t], red[t + o]); __syncthreads(); }
  if (t == 0) stash[2] = red[0];
  __syncthreads();
  red[t] = sfp; __syncthreads();
  for (int o = 128; o > 0; o >>= 1) { if (t < o) red[t] += red[t + o]; __syncthreads(); }
  if (t == 0) {
    float fwd = stash[0] + PENALTY * ((float)NSF - red[0]);
    float rev = stash[1] * (REV_SCALE / (stash[2] + EPSF));
    out[0] = fwd + rev;
  }
}

extern "C" void kernel_launch(void* const* d_in, const int* in_sizes, int n_in,
                              void* d_out, int out_size, void* d_ws, size_t ws_size,
                              hipStream_t stream) {
  const float* ov  = (const float*)d_in[0];
  const int*   ofc = (const int*)  d_in[1];
  const float* sv  = (const float*)d_in[2];
  const int*   sfc = (const int*)  d_in[3];
  const float* fp  = (const float*)d_in[4];
  float* out = (float*)d_out;

  int NOV = in_sizes[0] / 3;
  int NOF = in_sizes[1] / 3;
  int NSF = in_sizes[3] / 3;
  int NFP = in_sizes[4];

  // ws layout: [acc 16KB][gsum 2KB][cnt][cs][cur][sorted]
  char* w = (char*)d_ws;
  float* acc = (float*)w;                            w += ACC_FLOATS * 4;  // 16 KB
  unsigned long long* gsum = (unsigned long long*)w; w += 2048;            // 2 KB
  int*   cnt = (int*)w;                              w += (size_t)NTOT2 * 4;
  size_t zeroBytes = (size_t)(w - (char*)d_ws);      // acc + gsum + cnt contiguous
  int*   cs  = (int*)w;                              w += (size_t)(NTOT2 + 16) * 4;
  int*   cur = (int*)w;                              w += (size_t)NTOT2 * 4;
  float4* sorted = (float4*)w;                       w += (size_t)(NOV + NOF) * 16;

  hipMemsetAsync(d_ws, 0, zeroBytes, stream);

  hipLaunchKernelGGL(prep_kernel, dim3((NOF + NOV + 255) / 256), dim3(256), 0, stream,
                     ov, ofc, cnt, NOF, NOV);

  hipLaunchKernelGGL(scan_kernel, dim3(SCAN_BLOCKS), dim3(256), 0, stream,
                     (const int4*)cnt, gsum, cs, cur);

  hipLaunchKernelGGL(scatter_kernel, dim3((NOV + NOF + 255) / 256), dim3(256), 0, stream,
                     ov, ofc, cur, sorted, NOV, NOF);

  int fwdBlocks = (NSF + (256 / GS) - 1) / (256 / GS);   // 16 fwd queries per block
  int revBlocks = (NSF + 3) / 4;                          // 4 faces (waves) per block
  hipLaunchKernelGGL(query_kernel, dim3(fwdBlocks + revBlocks), dim3(256), 0, stream,
                     ov, sv, sfc, fp, cs, sorted, acc, out, NSF, NFP, fwdBlocks);
}

// Round 8
// 377.414 us; speedup vs baseline: 7.2827x; 7.2827x over previous
//
#include <hip/hip_runtime.h>
#include <stdint.h>
#include <float.h>

#define NUM_SAMPLES 50
#define EPSF 1e-8f
#define PENALTY 1e-4f
#define REV_SCALE 0.1f

// grid 1: original vertices (N(0,1) coords)
#define G1 48
#define G1LO -5.0f
#define G1HI 5.0f
#define NCELL1 (G1*G1*G1)
// grid 2: original-face barycenters (sigma ~0.577)
#define G2 48
#define G2LO -3.5f
#define G2HI 3.5f
#define NCELL2 (G2*G2*G2)
// grid 3: sample-point buckets (query batching)
#define G3 32
#define G3LO -5.0f
#define G3HI 5.0f
#define NCELL3 (G3*G3*G3)

#define NTOTALL (NCELL1 + NCELL2 + NCELL3)   // 253952
#define NB 248                               // build blocks (co-resident on 256 CUs)
static_assert(NTOTALL == NB * 1024, "scan tiling");

#define GS 16           // lanes per forward query group
#define REV_BLOCKS 1024 // reverse query blocks (4 waves each)

// acc floats: fwd slots [0..1023] s16; rev [1024..2047]; max bits [2048..3071];
// done ctr int @3072; nwork int @3076. 16 KB.
#define ACC_FLOATS 4096

// ---------------- JAX threefry2x32 (exact) ----------------
__device__ __forceinline__ uint32_t rotl32(uint32_t v, int d) {
  return (v << d) | (v >> (32 - d));
}

__device__ __forceinline__ void threefry2x32(uint32_t k0, uint32_t k1,
                                             uint32_t x0, uint32_t x1,
                                             uint32_t& o0, uint32_t& o1) {
  const uint32_t k2 = k0 ^ k1 ^ 0x1BD11BDAu;
  x0 += k0; x1 += k1;
#define TF_ROUND(r) { x0 += x1; x1 = rotl32(x1, (r)); x1 ^= x0; }
  TF_ROUND(13) TF_ROUND(15) TF_ROUND(26) TF_ROUND(6)
  x0 += k1; x1 += k2 + 1u;
  TF_ROUND(17) TF_ROUND(29) TF_ROUND(16) TF_ROUND(24)
  x0 += k2; x1 += k0 + 2u;
  TF_ROUND(13) TF_ROUND(15) TF_ROUND(26) TF_ROUND(6)
  x0 += k0; x1 += k1 + 3u;
  TF_ROUND(17) TF_ROUND(29) TF_ROUND(16) TF_ROUND(24)
  x0 += k1; x1 += k2 + 4u;
  TF_ROUND(13) TF_ROUND(15) TF_ROUND(26) TF_ROUND(6)
  x0 += k2; x1 += k0 + 5u;
#undef TF_ROUND
  o0 = x0; o1 = x1;
}

__device__ __forceinline__ float bits_to_uniform(uint32_t bits) {
  return __uint_as_float((bits >> 9) | 0x3f800000u) - 1.0f;
}

__device__ __forceinline__ float jax_uniform_at(uint32_t k0, uint32_t k1, uint32_t idx) {
  uint32_t o0, o1;
  threefry2x32(k0, k1, 0u, idx, o0, o1);
  return bits_to_uniform(o0 ^ o1);
}

__device__ __forceinline__ int cell_coord(float p, float lo, float invh, int G) {
  int i = (int)floorf((p - lo) * invh);
  return min(max(i, 0), G - 1);
}

// sample id -> position + weight (exact JAX RNG; partitionable split of key(42))
__device__ __forceinline__ float4 gen_sample(int id, const float* __restrict__ sv,
                                             const int* __restrict__ sfc,
                                             const float* __restrict__ fp, int NFP) {
  int face = id / NUM_SAMPLES;
  uint32_t a0, a1, b0, b1;
  threefry2x32(0u, 42u, 0u, 0u, a0, a1);  // rk1
  threefry2x32(0u, 42u, 0u, 1u, b0, b1);  // rk2
  float r1 = jax_uniform_at(a0, a1, (uint32_t)id);
  float r2 = jax_uniform_at(b0, b1, (uint32_t)id);
  float sr1 = sqrtf(r1);
  float ca = 1.0f - sr1;
  float cb = sr1 * (1.0f - r2);
  float cc = sr1 * r2;
  int va = sfc[3*face], vb = sfc[3*face+1], vc = sfc[3*face+2];
  float px = ca*sv[3*va]   + cb*sv[3*vb]   + cc*sv[3*vc];
  float py = ca*sv[3*va+1] + cb*sv[3*vb+1] + cc*sv[3*vc+1];
  float pz = ca*sv[3*va+2] + cb*sv[3*vb+2] + cc*sv[3*vc+2];
  float w = (face < NFP) ? fp[face] : 0.0f;
  return make_float4(px, py, pz, w);
}

// distributed grid barrier: per-block publish line + per-lane poll (no single hot ctr)
__device__ __forceinline__ void dbarrier(int* bar, int phase) {
  __syncthreads();
  if (threadIdx.x == 0) {
    __threadfence();
    atomicExch(&bar[blockIdx.x], phase);
  }
  if (threadIdx.x < NB) {
    while (atomicAdd(&bar[threadIdx.x], 0) < phase) { }
  }
  __syncthreads();
}

// ---------------- build: histogram -> B1 -> scan+workgen -> B2 -> scatter
__global__ __launch_bounds__(256) void build_kernel(
    const float* __restrict__ ov, const int* __restrict__ ofc,
    const float* __restrict__ sv, const int* __restrict__ sfc,
    const float* __restrict__ fp,
    int* __restrict__ cnt, int* __restrict__ cs, int* __restrict__ cur,
    unsigned long long* __restrict__ gsum, int* __restrict__ bar,
    float4* __restrict__ sorted, int* __restrict__ workArr, int* __restrict__ nwork,
    int NOF, int NSF, int NOV, int NFP, int nsamp) {
  int t = threadIdx.x, b = blockIdx.x;
  int tid = b * 256 + t;
  const int NT = NB * 256;
  const int sampBase = NOV + NOF;
  const float invh1 = (float)G1 / (G1HI - G1LO);
  const float invh2 = (float)G2 / (G2HI - G2LO);
  const float invh3 = (float)G3 / (G3HI - G3LO);

  // ---- phase H: histograms (cnt zeroed by host memset) ----
  {
    int total = NOF + NOV + nsamp;
    for (int i = tid; i < total; i += NT) {
      if (i < NOF) {
        int a = ofc[3*i], b2 = ofc[3*i+1], c2 = ofc[3*i+2];
        float x = (ov[3*a]   + ov[3*b2]   + ov[3*c2])   / 3.0f;
        float y = (ov[3*a+1] + ov[3*b2+1] + ov[3*c2+1]) / 3.0f;
        float z = (ov[3*a+2] + ov[3*b2+2] + ov[3*c2+2]) / 3.0f;
        int cx = cell_coord(x, G2LO, invh2, G2);
        int cy = cell_coord(y, G2LO, invh2, G2);
        int cz = cell_coord(z, G2LO, invh2, G2);
        atomicAdd(&cnt[NCELL1 + (cz*G2 + cy)*G2 + cx], 1);
      } else if (i < NOF + NOV) {
        int j = i - NOF;
        float x = ov[3*j], y = ov[3*j+1], z = ov[3*j+2];
        int cx = cell_coord(x, G1LO, invh1, G1);
        int cy = cell_coord(y, G1LO, invh1, G1);
        int cz = cell_coord(z, G1LO, invh1, G1);
        atomicAdd(&cnt[(cz*G1 + cy)*G1 + cx], 1);
      } else {
        int j = i - NOF - NOV;
        float4 s = gen_sample(j, sv, sfc, fp, NFP);
        int cx = cell_coord(s.x, G3LO, invh3, G3);
        int cy = cell_coord(s.y, G3LO, invh3, G3);
        int cz = cell_coord(s.z, G3LO, invh3, G3);
        atomicAdd(&cnt[NCELL1 + NCELL2 + (cz*G3 + cy)*G3 + cx], 1);
      }
    }
  }
  dbarrier(bar, 1);

  // ---- phase S: scan (block-local + gsum publish/poll) + G3 work-item gen ----
  {
    __shared__ int lds[256];
    __shared__ int wsum[4];
    __shared__ int boffS;
    int gid = b * 256 + t;
    int4 c;
    c.x = atomicAdd(&cnt[4*gid],   0);
    c.y = atomicAdd(&cnt[4*gid+1], 0);
    c.z = atomicAdd(&cnt[4*gid+2], 0);
    c.w = atomicAdd(&cnt[4*gid+3], 0);
    int s01 = c.x + c.y;
    int tsum = s01 + c.z + c.w;
    lds[t] = tsum;
    __syncthreads();
    for (int d = 1; d < 256; d <<= 1) {
      int u = (t >= d) ? lds[t - d] : 0;
      __syncthreads();
      lds[t] += u;
      __syncthreads();
    }
    int incl = lds[t];
    int agg  = lds[255];
    if (t == 0)
      atomicExch(&gsum[b], (1ULL << 63) | (unsigned long long)(unsigned)agg);
    int pre = 0;
    if (t < b) {
      unsigned long long v;
      do { v = atomicAdd(&gsum[t], 0ULL); } while (!(v >> 63));
      pre = (int)(v & 0xFFFFFFFFULL);
    }
    for (int o = 32; o > 0; o >>= 1) pre += __shfl_down(pre, o);
    if ((t & 63) == 0) wsum[t >> 6] = pre;
    __syncthreads();
    if (t == 0) boffS = wsum[0] + wsum[1] + wsum[2] + wsum[3];
    __syncthreads();
    int base = boffS + incl - tsum;
    int st[4], ct[4];
    st[0] = base;         ct[0] = c.x;
    st[1] = base + c.x;   ct[1] = c.y;
    st[2] = base + s01;   ct[2] = c.z;
    st[3] = st[2] + c.z;  ct[3] = c.w;
    // cs: plain (consumed next dispatch). cur: atomic (consumed cross-XCD in phase T)
    int4 o4; o4.x = st[0]; o4.y = st[1]; o4.z = st[2]; o4.w = st[3];
    ((int4*)cs)[gid] = o4;
    atomicExch(&cur[4*gid],   st[0]);
    atomicExch(&cur[4*gid+1], st[1]);
    atomicExch(&cur[4*gid+2], st[2]);
    atomicExch(&cur[4*gid+3], st[3]);
    if (b == NB - 1 && t == 255) cs[NTOTALL] = boffS + incl;
    // work items for G3 cells (offsets are in registers here)
    const int c3lo = NCELL1 + NCELL2;
#pragma unroll
    for (int k = 0; k < 4; ++k) {
      int cellIdx = 4*gid + k;
      if (cellIdx >= c3lo && ct[k] > 0) {
        int rel = st[k] - sampBase;
        for (int off = 0; off < ct[k]; off += 64) {
          int len = min(ct[k] - off, 64);
          int it = atomicAdd(nwork, 1);
          workArr[it] = (rel + off) | (len << 20);  // plain store, next dispatch
        }
      }
    }
  }
  dbarrier(bar, 2);

  // ---- phase T: scatter all points into cell-sorted order ----
  {
    int nsc = NOV + NOF + nsamp;
    for (int i = tid; i < nsc; i += NT) {
      float4 p; int cell;
      if (i < NOV) {
        float x = ov[3*i], y = ov[3*i+1], z = ov[3*i+2];
        p = make_float4(x, y, z, x*x + y*y + z*z);
        int cx = cell_coord(x, G1LO, invh1, G1);
        int cy = cell_coord(y, G1LO, invh1, G1);
        int cz = cell_coord(z, G1LO, invh1, G1);
        cell = (cz*G1 + cy)*G1 + cx;
      } else if (i < NOV + NOF) {
        int j = i - NOV;
        int a = ofc[3*j], b2 = ofc[3*j+1], c2 = ofc[3*j+2];
        float x = (ov[3*a]   + ov[3*b2]   + ov[3*c2])   / 3.0f;
        float y = (ov[3*a+1] + ov[3*b2+1] + ov[3*c2+1]) / 3.0f;
        float z = (ov[3*a+2] + ov[3*b2+2] + ov[3*c2+2]) / 3.0f;
        p = make_float4(x, y, z, x*x + y*y + z*z);
        int cx = cell_coord(x, G2LO, invh2, G2);
        int cy = cell_coord(y, G2LO, invh2, G2);
        int cz = cell_coord(z, G2LO, invh2, G2);
        cell = NCELL1 + (cz*G2 + cy)*G2 + cx;
      } else {
        p = gen_sample(i - NOV - NOF, sv, sfc, fp, NFP);  // w = face prob
        int cx = cell_coord(p.x, G3LO, invh3, G3);
        int cy = cell_coord(p.y, G3LO, invh3, G3);
        int cz = cell_coord(p.z, G3LO, invh3, G3);
        cell = NCELL1 + NCELL2 + (cz*G3 + cy)*G3 + cx;
      }
      int idx = atomicAdd(&cur[cell], 1);
      sorted[idx] = p;
    }
  }
}

// ---------------- forward: row-parallel 16-lane 1-NN (R6-proven)
__device__ __forceinline__ float group_min16(float v) {
  for (int o = 8; o > 0; o >>= 1) v = fminf(v, __shfl_xor(v, o, 16));
  return v;
}

__device__ float nn_group(float px, float py, float pz, float q2,
                          const int* __restrict__ cs, const float4* __restrict__ pts,
                          int G, float lo, float h, int cellofs, int lane) {
  const float invh = 1.0f / h;
  int ix = cell_coord(px, lo, invh, G);
  int iy = cell_coord(py, lo, invh, G);
  int iz = cell_coord(pz, lo, invh, G);
  float m2x = -2.0f*px, m2y = -2.0f*py, m2z = -2.0f*pz;
  float best = FLT_MAX;
  {
    int cix = cellofs + (iz*G + iy)*G + ix;
    int s = cs[cix], e = cs[cix + 1];
    for (int i = s + lane; i < e; i += GS) {
      float4 v = pts[i];
      best = fminf(best, fmaf(v.z, m2z, fmaf(v.y, m2y, fmaf(v.x, m2x, v.w))));
    }
  }
  for (int r = 1; r < G; ++r) {
    float bmin = group_min16(best);
    float bd = (float)(r - 1) * h;
    if (bmin + q2 <= bd * bd) break;
    float dbest = bmin + q2;
    int z0 = max(iz - r, 0), z1 = min(iz + r, G - 1);
    int y0 = max(iy - r, 0), y1 = min(iy + r, G - 1);
    int x0 = max(ix - r, 0), x1 = min(ix + r, G - 1);
    int Y = y1 - y0 + 1;
    int nrows = Y * (z1 - z0 + 1);
    for (int rowi = lane; rowi < nrows; rowi += GS) {
      int zz = z0 + rowi / Y;
      int yy = y0 + rowi % Y;
      int adz = abs(zz - iz), ady = abs(yy - iy);
      float lbz = (adz > 0) ? (float)(adz - 1) * h : 0.0f;
      float lby = (ady > 0) ? (float)(ady - 1) * h : 0.0f;
      float lb2 = lbz*lbz + lby*lby;
      int rowbase = cellofs + (zz*G + yy)*G;
      if (adz == r || ady == r) {
        if (lb2 >= dbest) continue;
        int s = cs[rowbase + x0], e = cs[rowbase + x1 + 1];
        for (int i = s; i < e; ++i) {
          float4 v = pts[i];
          best = fminf(best, fmaf(v.z, m2z, fmaf(v.y, m2y, fmaf(v.x, m2x, v.w))));
        }
      } else {
        float lbx = (float)(r - 1) * h;
        if (lb2 + lbx*lbx >= dbest) continue;
        if (ix - r >= 0) {
          int cix = rowbase + ix - r;
          int s = cs[cix], e = cs[cix + 1];
          for (int i = s; i < e; ++i) {
            float4 v = pts[i];
            best = fminf(best, fmaf(v.z, m2z, fmaf(v.y, m2y, fmaf(v.x, m2x, v.w))));
          }
        }
        if (ix + r <= G - 1) {
          int cix = rowbase + ix + r;
          int s = cs[cix], e = cs[cix + 1];
          for (int i = s; i < e; ++i) {
            float4 v = pts[i];
            best = fminf(best, fmaf(v.z, m2z, fmaf(v.y, m2y, fmaf(v.x, m2x, v.w))));
          }
        }
      }
    }
  }
  return group_min16(best);
}

__device__ __forceinline__ float wave_max64(float v) {
  for (int o = 32; o > 0; o >>= 1) v = fmaxf(v, __shfl_xor(v, o));
  return v;
}

// ---------------- queries: fwd 16-lane groups + rev cell-batched waves
__global__ __launch_bounds__(256) void query_kernel(
    const float* __restrict__ sv, const int* __restrict__ sfc,
    const float* __restrict__ fp,
    const int* __restrict__ cs, const float4* __restrict__ sorted,
    const int* __restrict__ workArr, const int* __restrict__ nworkPtr,
    float* __restrict__ acc, float* __restrict__ out,
    int NSF, int NFP, int nsamp, int sampBase, int fwdBlocks) {
  const float h1 = (G1HI - G1LO) / (float)G1;
  const float h2 = (G2HI - G2LO) / (float)G2;
  float facc = 0.0f, racc = 0.0f, rmaxv = 0.0f;

  if ((int)blockIdx.x < fwdBlocks) {
    // ---- forward: simplified-face barycenter -> nearest original barycenter ----
    int lane = threadIdx.x & (GS - 1);
    int g = blockIdx.x * (256 / GS) + threadIdx.x / GS;
    if (g < NSF) {
      int a = sfc[3*g], b = sfc[3*g+1], c = sfc[3*g+2];
      float x = (sv[3*a]   + sv[3*b]   + sv[3*c])   / 3.0f;
      float y = (sv[3*a+1] + sv[3*b+1] + sv[3*c+1]) / 3.0f;
      float z = (sv[3*a+2] + sv[3*b+2] + sv[3*c+2]) / 3.0f;
      float q2 = x*x + y*y + z*z;
      float best = nn_group(x, y, z, q2, cs, sorted, G2, G2LO, h2, NCELL1, lane);
      if (lane == 0) {
        float mind = sqrtf(fmaxf(best + q2, 0.0f));
        float p = (g < NFP) ? fp[g] : 0.0f;
        facc = p * mind;
      }
    }
  } else {
    // ---- reverse: one wave per <=64-sample chunk of ONE G3 cell ----
    int lane = threadIdx.x & 63;
    int totWaves = ((int)gridDim.x - fwdBlocks) * 4;
    int wv0 = ((int)blockIdx.x - fwdBlocks) * 4 + (threadIdx.x >> 6);
    int nw = nworkPtr[0];
    const float invh1 = 1.0f / h1;
    const float4* SS = sorted + sampBase;
    for (int iw = wv0; iw < nw; iw += totWaves) {
      int packed = workArr[iw];
      int rel = packed & 0xFFFFF;
      int len = packed >> 20;
      bool valid = lane < len;
      float4 s = SS[rel + (valid ? lane : 0)];
      float q2 = s.x*s.x + s.y*s.y + s.z*s.z;
      float m2x = -2.0f*s.x, m2y = -2.0f*s.y, m2z = -2.0f*s.z;
      // chunk AABB (true coords)
      float mnx = valid ? s.x :  FLT_MAX, mxx = valid ? s.x : -FLT_MAX;
      float mny = valid ? s.y :  FLT_MAX, mxy = valid ? s.y : -FLT_MAX;
      float mnz = valid ? s.z :  FLT_MAX, mxz = valid ? s.z : -FLT_MAX;
      for (int o = 32; o > 0; o >>= 1) {
        mnx = fminf(mnx, __shfl_xor(mnx, o)); mxx = fmaxf(mxx, __shfl_xor(mxx, o));
        mny = fminf(mny, __shfl_xor(mny, o)); mxy = fmaxf(mxy, __shfl_xor(mxy, o));
        mnz = fminf(mnz, __shfl_xor(mnz, o)); mxz = fmaxf(mxz, __shfl_xor(mxz, o));
      }
      int bx0 = cell_coord(mnx, G1LO, invh1, G1), bx1 = cell_coord(mxx, G1LO, invh1, G1);
      int by0 = cell_coord(mny, G1LO, invh1, G1), by1 = cell_coord(mxy, G1LO, invh1, G1);
      int bz0 = cell_coord(mnz, G1LO, invh1, G1), bz1 = cell_coord(mxz, G1LO, invh1, G1);
      // clamp-overflow slack (zero unless samples fall outside the grid domain)
      float dl = 0.0f;
      dl = fmaxf(dl, ((float)bx0 * h1 + G1LO) - mnx);
      dl = fmaxf(dl, mxx - ((float)(bx1 + 1) * h1 + G1LO));
      dl = fmaxf(dl, ((float)by0 * h1 + G1LO) - mny);
      dl = fmaxf(dl, mxy - ((float)(by1 + 1) * h1 + G1LO));
      dl = fmaxf(dl, ((float)bz0 * h1 + G1LO) - mnz);
      dl = fmaxf(dl, mxz - ((float)(bz1 + 1) * h1 + G1LO));

      float best = valid ? FLT_MAX : -FLT_MAX;
      int px0 = 0, px1 = -1, py0 = 0, py1 = -1, pz0 = 0, pz1 = -1;
      for (int r = 0; r < G1; ++r) {
        int ax0 = max(bx0 - r, 0), ax1 = min(bx1 + r, G1 - 1);
        int ay0 = max(by0 - r, 0), ay1 = min(by1 + r, G1 - 1);
        int az0 = max(bz0 - r, 0), az1 = min(bz1 + r, G1 - 1);
        float m = wave_max64(best + q2);   // worst current d^2
        if (r >= 1) {
          float bd = fmaxf((float)(r - 1) * h1 - dl, 0.0f);
          if (m <= bd * bd) break;
          if (ax0 == px0 && ax1 == px1 && ay0 == py0 && ay1 == py1 &&
              az0 == pz0 && az1 == pz1) break;
        }
        int EX = ax1 - ax0 + 1, EY = ay1 - ay0 + 1;
        int vol = EX * EY * (az1 - az0 + 1);
        for (int basei = 0; basei < vol; basei += 64) {
          int li = basei + lane;
          int sC = 0, eC = 0;
          if (li < vol) {
            int xx = li % EX; int tmp = li / EX;
            int yy = tmp % EY; int zz = tmp / EY;
            int gx = ax0 + xx, gy = ay0 + yy, gz = az0 + zz;
            bool inPrev = gx >= px0 && gx <= px1 && gy >= py0 && gy <= py1 &&
                          gz >= pz0 && gz <= pz1;
            if (!inPrev) {
              int cdx = max(max(bx0 - gx, gx - bx1), 0);
              int cdy = max(max(by0 - gy, gy - by1), 0);
              int cdz = max(max(bz0 - gz, gz - bz1), 0);
              float lx = (cdx > 0) ? fmaxf((float)(cdx - 1) * h1 - dl, 0.0f) : 0.0f;
              float ly = (cdy > 0) ? fmaxf((float)(cdy - 1) * h1 - dl, 0.0f) : 0.0f;
              float lz = (cdz > 0) ? fmaxf((float)(cdz - 1) * h1 - dl, 0.0f) : 0.0f;
              if (lx*lx + ly*ly + lz*lz < m) {
                int cell = (gz*G1 + gy)*G1 + gx;
                sC = cs[cell]; eC = cs[cell + 1];
              }
            }
          }
          unsigned long long mask = __ballot(sC < eC);
          while (mask) {
            int src = __ffsll((unsigned long long)mask) - 1;
            mask &= mask - 1;
            int a = __shfl(sC, src), e = __shfl(eC, src);
            for (int j = a; j < e; ++j) {
              float4 v = sorted[j];   // broadcast load serves all 64 queries
              best = fminf(best, fmaf(v.z, m2z, fmaf(v.y, m2y, fmaf(v.x, m2x, v.w))));
            }
          }
        }
        px0 = ax0; px1 = ax1; py0 = ay0; py1 = ay1; pz0 = az0; pz1 = az1;
      }
      float d = valid ? sqrtf(fmaxf(best + q2, 0.0f)) : 0.0f;
      racc += (valid ? s.w : 0.0f) * d;
      rmaxv = fmaxf(rmaxv, d);
    }
  }

  // ---- block reduce + slot atomics + last-block finalize ----
  __shared__ float sF[4], sR[4], sM[4];
  __shared__ int isLast;
  __shared__ float stash[4];
  for (int o = 32; o > 0; o >>= 1) {
    facc += __shfl_down(facc, o);
    racc += __shfl_down(racc, o);
    rmaxv = fmaxf(rmaxv, __shfl_down(rmaxv, o));
  }
  int wid = threadIdx.x >> 6;
  if ((threadIdx.x & 63) == 0) { sF[wid] = facc; sR[wid] = racc; sM[wid] = rmaxv; }
  __syncthreads();
  if (threadIdx.x == 0) {
    float tf = sF[0] + sF[1] + sF[2] + sF[3];
    float tr = sR[0] + sR[1] + sR[2] + sR[3];
    float tm = fmaxf(fmaxf(sM[0], sM[1]), fmaxf(sM[2], sM[3]));
    int slot = (blockIdx.x & 63) * 16;
    atomicAdd(&acc[slot], tf);
    atomicAdd(&acc[1024 + slot], tr);
    atomicMax((int*)acc + 2048 + slot, __float_as_int(tm));
    __threadfence();
    int old = atomicAdd((int*)acc + 3072, 1);
    isLast = (old == (int)gridDim.x - 1) ? 1 : 0;
  }
  __syncthreads();
  if (!isLast) return;

  __shared__ float red[256];
  int t = threadIdx.x;
  float fsum = 0.0f, rsum = 0.0f, rmx = 0.0f;
  if (t < 64)        fsum = atomicAdd(&acc[t * 16], 0.0f);
  else if (t < 128)  rsum = atomicAdd(&acc[1024 + (t - 64) * 16], 0.0f);
  else if (t < 192)  rmx  = __int_as_float(atomicMax((int*)acc + 2048 + (t - 128) * 16, 0));
  float sfp = 0.0f;
  for (int i = t; i < NSF; i += 256) sfp += (i < NFP) ? fp[i] : 0.0f;

  red[t] = fsum; __syncthreads();
  for (int o = 128; o > 0; o >>= 1) { if (t < o) red[t] += red[t + o]; __syncthreads(); }
  if (t == 0) stash[0] = red[0];
  __syncthreads();
  red[t] = rsum; __syncthreads();
  for (int o = 128; o > 0; o >>= 1) { if (t < o) red[t] += red[t + o]; __syncthreads(); }
  if (t == 0) stash[1] = red[0];
  __syncthreads();
  red[t] = rmx; __syncthreads();
  for (int o = 128; o > 0; o >>= 1) { if (t < o) red[t] = fmaxf(red[t], red[t + o]); __syncthreads(); }
  if (t == 0) stash[2] = red[0];
  __syncthreads();
  red[t] = sfp; __syncthreads();
  for (int o = 128; o > 0; o >>= 1) { if (t < o) red[t] += red[t + o]; __syncthreads(); }
  if (t == 0) {
    float fwd = stash[0] + PENALTY * ((float)NSF - red[0]);
    float rev = stash[1] * (REV_SCALE / (stash[2] + EPSF));
    out[0] = fwd + rev;
  }
}

extern "C" void kernel_launch(void* const* d_in, const int* in_sizes, int n_in,
                              void* d_out, int out_size, void* d_ws, size_t ws_size,
                              hipStream_t stream) {
  const float* ov  = (const float*)d_in[0];
  const int*   ofc = (const int*)  d_in[1];
  const float* sv  = (const float*)d_in[2];
  const int*   sfc = (const int*)  d_in[3];
  const float* fp  = (const float*)d_in[4];
  float* out = (float*)d_out;

  int NOV = in_sizes[0] / 3;
  int NOF = in_sizes[1] / 3;
  int NSF = in_sizes[3] / 3;
  int NFP = in_sizes[4];
  int nsamp = NSF * NUM_SAMPLES;
  int sampBase = NOV + NOF;

  // ws: [acc 16KB][gsum 2KB][bar 1KB][cnt] (zeroed) | [cs][cur][sorted][work]
  char* w = (char*)d_ws;
  float* acc = (float*)w;                            w += ACC_FLOATS * 4;
  unsigned long long* gsum = (unsigned long long*)w; w += 2048;
  int*   bar = (int*)w;                              w += 1024;
  int*   cnt = (int*)w;                              w += (size_t)NTOTALL * 4;
  size_t zeroBytes = (size_t)(w - (char*)d_ws);
  int*   cs  = (int*)w;                              w += (size_t)(NTOTALL + 16) * 4;
  int*   cur = (int*)w;                              w += (size_t)NTOTALL * 4;
  float4* sorted = (float4*)w;                       w += (size_t)(sampBase + nsamp) * 16;
  int*   workArr = (int*)w;                          w += (size_t)(nsamp / 64 + NCELL3 + 64) * 4;
  int*   nwork = (int*)acc + 3076;

  hipMemsetAsync(d_ws, 0, zeroBytes, stream);

  hipLaunchKernelGGL(build_kernel, dim3(NB), dim3(256), 0, stream,
                     ov, ofc, sv, sfc, fp, cnt, cs, cur, gsum, bar,
                     sorted, workArr, nwork, NOF, NSF, NOV, NFP, nsamp);

  int fwdBlocks = (NSF + (256 / GS) - 1) / (256 / GS);
  hipLaunchKernelGGL(query_kernel, dim3(fwdBlocks + REV_BLOCKS), dim3(256), 0, stream,
                     sv, sfc, fp, cs, sorted, workArr, nwork, acc, out,
                     NSF, NFP, nsamp, sampBase, fwdBlocks);
}